// Round 1
// baseline (3953.011 us; speedup 1.0000x reference)
//
#include <hip/hip_runtime.h>

// DOC_Retriever: sim = (q/|q|) @ (f/|f|)^T, top-5 per query row, gather data rows.
// Ranking trick: |q_b| is a per-row positive constant -> skip q normalization.
// Kernel 1: fp32 tiled GEMM (64b x 128n block tile, 4x8 thread tile, K staged in
//           LDS chunks of 64) fused with f-norms (computed during staging) and
//           per-block per-row top-5 -> partials[b][blk][5] as sortable u64 keys.
// Kernel 2: per-row merge of nblk*5 candidates + gather of data[idx] -> out.

#define TN 128
#define TK 64
#define LDS_STRIDE (TK + 4)   // +4 floats: keeps float4 16B-aligned, ~2-way banks
#define D_DIM 768
#define B_DIM 64
#define KTOP 5
#define SEG 512

__device__ __forceinline__ unsigned long long shfl_xor_u64(unsigned long long x, int m, int w) {
    int lo = __shfl_xor((int)(unsigned)x, m, w);
    int hi = __shfl_xor((int)(unsigned)(x >> 32), m, w);
    return ((unsigned long long)(unsigned)hi << 32) | (unsigned)lo;
}

// insert into descending sorted list of 5 (single bubble pass)
__device__ __forceinline__ void ins5(unsigned long long (&L)[5], unsigned long long key) {
    if (key <= L[4]) return;
    L[4] = key;
#pragma unroll
    for (int s = 4; s > 0; --s) {
        if (L[s] > L[s - 1]) { unsigned long long t = L[s]; L[s] = L[s - 1]; L[s - 1] = t; }
    }
}

// sortable key: monotone float->u32, then | ~index (prefers smaller index on ties,
// matching top_k tie-break); index recovered as ~(u32)key.
__device__ __forceinline__ unsigned long long make_key(float val, int gn) {
    unsigned u = __float_as_uint(val);
    unsigned key32 = (u & 0x80000000u) ? ~u : (u | 0x80000000u);
    return ((unsigned long long)key32 << 32) | (unsigned)(~(unsigned)gn);
}

__global__ __launch_bounds__(256)
void k_sim_partial(const float* __restrict__ q, const float* __restrict__ f,
                   unsigned long long* __restrict__ partials, int N, int nblk)
{
    __shared__ float qs[B_DIM][LDS_STRIDE];
    __shared__ float fs[TN][LDS_STRIDE];
    __shared__ float fnorm[TN];

    const int tid = threadIdx.x;
    const int tx = tid & 15;       // 16 n-groups: n_local = tx + 16*j
    const int ty = tid >> 4;       // 16 b-groups: b = 4*ty + i
    const int n0 = blockIdx.x * TN;

    float c[4][8];
#pragma unroll
    for (int i = 0; i < 4; ++i)
#pragma unroll
        for (int j = 0; j < 8; ++j) c[i][j] = 0.f;

    float psq[8];   // sum-of-squares partials for feature rows ty+16v
#pragma unroll
    for (int v = 0; v < 8; ++v) psq[v] = 0.f;

    for (int kc = 0; kc < D_DIM / TK; ++kc) {
        const int d0 = kc * TK;
        float4 qv[4], fv[8];
#pragma unroll
        for (int v = 0; v < 4; ++v) {
            int idx = tid + 256 * v;
            int r = idx >> 4, c4 = idx & 15;
            qv[v] = *(const float4*)&q[(size_t)r * D_DIM + d0 + c4 * 4];
        }
#pragma unroll
        for (int v = 0; v < 8; ++v) {
            int r = ty + 16 * v;
            int gn = n0 + r;
            float4 z; z.x = z.y = z.z = z.w = 0.f;
            fv[v] = (gn < N) ? *(const float4*)&f[(size_t)gn * D_DIM + d0 + tx * 4] : z;
            psq[v] += fv[v].x * fv[v].x + fv[v].y * fv[v].y
                    + fv[v].z * fv[v].z + fv[v].w * fv[v].w;
        }
        __syncthreads();
#pragma unroll
        for (int v = 0; v < 4; ++v) {
            int idx = tid + 256 * v;
            int r = idx >> 4, c4 = idx & 15;
            *(float4*)&qs[r][c4 * 4] = qv[v];
        }
#pragma unroll
        for (int v = 0; v < 8; ++v) {
            int r = ty + 16 * v;
            *(float4*)&fs[r][tx * 4] = fv[v];
        }
        __syncthreads();
#pragma unroll
        for (int kk = 0; kk < TK / 4; ++kk) {
            float4 a[4], bb[8];
#pragma unroll
            for (int i = 0; i < 4; ++i) a[i] = *(const float4*)&qs[4 * ty + i][kk * 4];
#pragma unroll
            for (int j = 0; j < 8; ++j) bb[j] = *(const float4*)&fs[tx + 16 * j][kk * 4];
#pragma unroll
            for (int i = 0; i < 4; ++i)
#pragma unroll
                for (int j = 0; j < 8; ++j) {
                    c[i][j] += a[i].x * bb[j].x;
                    c[i][j] += a[i].y * bb[j].y;
                    c[i][j] += a[i].z * bb[j].z;
                    c[i][j] += a[i].w * bb[j].w;
                }
        }
    }

    // reduce feature-row sum-of-squares across the 16 lanes sharing each row
#pragma unroll
    for (int v = 0; v < 8; ++v) {
#pragma unroll
        for (int m = 1; m < 16; m <<= 1) psq[v] += __shfl_xor(psq[v], m, 16);
        if (tx == 0) fnorm[ty + 16 * v] = psq[v];
    }
    __syncthreads();

    // per-row top-5 over this block's 128 columns
#pragma unroll 1
    for (int i = 0; i < 4; ++i) {
        const int b = 4 * ty + i;
        unsigned long long L[5] = {0ull, 0ull, 0ull, 0ull, 0ull};
#pragma unroll
        for (int j = 0; j < 8; ++j) {
            int nl = tx + 16 * j;
            int gn = n0 + nl;
            float val = c[i][j] * rsqrtf(fnorm[nl]);
            unsigned long long key = make_key(val, gn);
            if (gn >= N) key = 0ull;   // guard tail rows (also kills NaN from 0*inf)
            ins5(L, key);
        }
        // merge 16 per-lane sorted-5 lists -> row top-5 via 5 butterfly-max rounds
        int h = 0;
#pragma unroll 1
        for (int r = 0; r < KTOP; ++r) {
            unsigned long long cand = (h < 5) ? L[h] : 0ull;
            unsigned long long m = cand;
#pragma unroll
            for (int off = 1; off < 16; off <<= 1) {
                unsigned long long o = shfl_xor_u64(m, off, 16);
                if (o > m) m = o;
            }
            if (h < 5 && cand == m && m != 0ull) ++h;   // winner pops (keys unique)
            if (tx == 0) partials[((size_t)b * nblk + blockIdx.x) * KTOP + r] = m;
        }
    }
}

__global__ __launch_bounds__(256)
void k_merge_gather(const unsigned long long* __restrict__ partials,
                    const int* __restrict__ data, int* __restrict__ out,
                    int nblk)
{
    const int b = blockIdx.x;
    const int tid = threadIdx.x;
    const int M = nblk * KTOP;
    const unsigned long long* p = partials + (size_t)b * M;

    unsigned long long L[5] = {0ull, 0ull, 0ull, 0ull, 0ull};
    for (int i = tid; i < M; i += 256) ins5(L, p[i]);

    __shared__ unsigned long long red[256];
    __shared__ int topIdx[KTOP];
    int h = 0;
#pragma unroll 1
    for (int r = 0; r < KTOP; ++r) {
        unsigned long long cand = (h < 5) ? L[h] : 0ull;
        red[tid] = cand;
        __syncthreads();
        for (int s = 128; s > 0; s >>= 1) {
            if (tid < s) { if (red[tid + s] > red[tid]) red[tid] = red[tid + s]; }
            __syncthreads();
        }
        unsigned long long win = red[0];
        if (h < 5 && cand == win && win != 0ull) ++h;
        if (tid == 0) topIdx[r] = (int)(~(unsigned)win);
        __syncthreads();
    }

    // gather 5 rows x 512 ints
    for (int e = tid; e < KTOP * SEG; e += 256) {
        int r = e >> 9, cc = e & (SEG - 1);
        out[((size_t)b * KTOP + r) * SEG + cc] = data[(size_t)topIdx[r] * SEG + cc];
    }
}

extern "C" void kernel_launch(void* const* d_in, const int* in_sizes, int n_in,
                              void* d_out, int out_size, void* d_ws, size_t ws_size,
                              hipStream_t stream) {
    const float* q = (const float*)d_in[0];     // (64, 768) f32
    const float* f = (const float*)d_in[1];     // (N, 768) f32
    const int* data = (const int*)d_in[2];      // (N, 512) i32
    // d_in[3] = k (always 5, hardcoded as KTOP)

    const int N = in_sizes[1] / D_DIM;          // 500000
    const int nblk = (N + TN - 1) / TN;         // 3907

    unsigned long long* partials = (unsigned long long*)d_ws;  // 64*nblk*5*8B ~= 10 MB

    k_sim_partial<<<nblk, 256, 0, stream>>>(q, f, partials, N, nblk);
    k_merge_gather<<<B_DIM, 256, 0, stream>>>(partials, data, (int*)d_out, nblk);
}